// Round 8
// baseline (899.504 us; speedup 1.0000x reference)
//
#include <hip/hip_runtime.h>

typedef unsigned short ushort_t;
typedef short short8 __attribute__((ext_vector_type(8)));
typedef float f32x4 __attribute__((ext_vector_type(4)));

// problem constants
#define NN   2048     // nodes
#define EE   8192     // edges
#define CC   128      // channels
#define HCC  512      // H*C
#define DFF  2048

#define BM 128
#define BN 128
#define BKK 64

enum { EPI_STORE_BIAS = 0, EPI_EXP = 1, EPI_GELU = 2, EPI_ATOMIC = 3 };

__device__ __forceinline__ float b2f(ushort_t u) {
    return __uint_as_float(((unsigned int)u) << 16);
}
__device__ __forceinline__ ushort_t f2b(float f) {
    unsigned int u = __float_as_uint(f);
    u += 0x7fffu + ((u >> 16) & 1u);   // round-to-nearest-even
    return (ushort_t)(u >> 16);
}

#define GLOAD16(gp, lp)                                                        \
    __builtin_amdgcn_global_load_lds(                                          \
        (const __attribute__((address_space(1))) unsigned int*)(gp),           \
        (__attribute__((address_space(3))) unsigned int*)(lp), 16, 0, 0)

// ---------------------------------------------------------------------------
// dtype probe: flags[0]=1 if float tensors are f32 (else bf16),
//              flags[1]=1 if index is int64 (else int32)
// ---------------------------------------------------------------------------
__global__ void probe_k(const void* __restrict__ x, const void* __restrict__ idx,
                        int* __restrict__ flags)
{
    if (threadIdx.x == 0 && blockIdx.x == 0) {
        const ushort_t* xu = (const ushort_t*)x;
        float mx = 0.f;
        for (int i = 0; i < 512; i++) {
            float v = fabsf(b2f(xu[i]));
            if (v < 1e30f) mx = fmaxf(mx, v);
            else mx = 1e30f;
        }
        flags[0] = (mx > 1e4f) ? 1 : 0;
        const int* ii = (const int*)idx;
        int allz = 1;
        for (int j = 1; j < 16; j += 2)
            if (ii[j] != 0) allz = 0;
        flags[1] = allz;
    }
}

__global__ void cvt_idx(const void* __restrict__ in, int* __restrict__ out,
                        const int* __restrict__ flags)
{
    int i = blockIdx.x * 256 + threadIdx.x;
    if (i < EE)
        out[i] = flags[1] ? (int)((const long long*)in)[i] : ((const int*)in)[i];
}

// ---------------------------------------------------------------------------
// Counting sort of edges by target (verified round 6).
// ---------------------------------------------------------------------------
__global__ __launch_bounds__(256)
void sort_edges(const int* __restrict__ idx, int* __restrict__ sorted_e,
                int* __restrict__ seg_off)
{
    __shared__ int hist[NN];
    __shared__ int cursor[NN];
    __shared__ float wsum[4];
    const int tid = threadIdx.x;
    for (int i = tid; i < NN; i += 256) hist[i] = 0;
    __syncthreads();
    for (int e = tid; e < EE; e += 256) atomicAdd(&hist[idx[e]], 1);
    __syncthreads();
    int s = 0;
#pragma unroll
    for (int j = 0; j < 8; j++) s += hist[tid * 8 + j];
    int lane = tid & 63, w = tid >> 6;
    int sc = s;
#pragma unroll
    for (int o = 1; o < 64; o <<= 1) {
        int t = __shfl_up(sc, o, 64);
        if (lane >= o) sc += t;
    }
    if (lane == 63) wsum[w] = (float)sc;
    __syncthreads();
    int wbase = 0;
    for (int j = 0; j < 4; j++) if (j < w) wbase += (int)wsum[j];
    int excl = wbase + sc - s;
    int run = excl;
#pragma unroll
    for (int j = 0; j < 8; j++) {
        int b = tid * 8 + j;
        cursor[b] = run;
        seg_off[b] = run;
        run += hist[b];
    }
    if (tid == 0) seg_off[NN] = EE;
    __syncthreads();
    for (int e = tid; e < EE; e += 256) {
        int pos = atomicAdd(&cursor[idx[e]], 1);
        sorted_e[pos] = e;
    }
}

// x -> bf16 copy (for MFMA) and f32 copy (for residual/LN)
__global__ void cvt_x(const void* __restrict__ in, ushort_t* __restrict__ xb,
                      float* __restrict__ xf, const int* __restrict__ flags)
{
    long i = (long)blockIdx.x * 256 + threadIdx.x;   // NN*CC
    float v = flags[0] ? ((const float*)in)[i] : b2f(((const ushort_t*)in)[i]);
    xf[i] = v;
    xb[i] = f2b(v);
}

// all 9 small vectors -> one canonical f32 buffer
__global__ void cvt_vecs(const void* bq, const void* bk, const void* bv,
                         const void* bz, const void* lnw, const void* lnb,
                         const void* b3, const void* b1, const void* b2,
                         float* __restrict__ out, const int* __restrict__ flags)
{
    int i = blockIdx.x * 256 + threadIdx.x;
    if (i >= 6144) return;
    const void* src; int o;
    if      (i < 512)  { src = bq;  o = i; }
    else if (i < 1024) { src = bk;  o = i - 512; }
    else if (i < 1536) { src = bv;  o = i - 1024; }
    else if (i < 1664) { src = bz;  o = i - 1536; }
    else if (i < 1792) { src = lnw; o = i - 1664; }
    else if (i < 1920) { src = lnb; o = i - 1792; }
    else if (i < 2048) { src = b3;  o = i - 1920; }
    else if (i < 4096) { src = b1;  o = i - 2048; }
    else               { src = b2;  o = i - 4096; }
    out[i] = flags[0] ? ((const float*)src)[o] : b2f(((const ushort_t*)src)[o]);
}

// weight transpose + convert to bf16: in [R,C] -> out [C,R] bf16
__global__ void transpose_cvt(const void* __restrict__ in, ushort_t* __restrict__ out,
                              int R, int C, const int* __restrict__ flags)
{
    __shared__ ushort_t t[32][33];
    const int f  = flags[0];
    const int bx = blockIdx.x * 32;
    const int by = blockIdx.y * 32;
    const int tx = threadIdx.x, ty = threadIdx.y;
#pragma unroll
    for (int i = 0; i < 32; i += 8) {
        long src = (long)(by + ty + i) * C + bx + tx;
        t[ty + i][tx] = f ? f2b(((const float*)in)[src]) : ((const ushort_t*)in)[src];
    }
    __syncthreads();
#pragma unroll
    for (int i = 0; i < 32; i += 8)
        out[(long)(bx + ty + i) * R + by + tx] = t[tx][ty + i];
}

// batched Wq/Wk/Wv transpose (all [128,512] -> [512,128])
__global__ void transpose_qkv(const void* q, const void* k, const void* v,
                              ushort_t* __restrict__ out, const int* __restrict__ flags)
{
    __shared__ ushort_t t[32][33];
    const void* in = blockIdx.z == 0 ? q : (blockIdx.z == 1 ? k : v);
    const int f  = flags[0];
    const int bx = blockIdx.x * 32;
    const int by = blockIdx.y * 32;
    const int tx = threadIdx.x, ty = threadIdx.y;
#pragma unroll
    for (int i = 0; i < 32; i += 8) {
        long src = (long)(by + ty + i) * HCC + bx + tx;
        t[ty + i][tx] = f ? f2b(((const float*)in)[src]) : ((const ushort_t*)in)[src];
    }
    __syncthreads();
#pragma unroll
    for (int i = 0; i < 32; i += 8)
        out[(size_t)blockIdx.z * HCC * CC + (long)(bx + ty + i) * CC + by + tx]
            = t[tx][ty + i];
}

// ---------------------------------------------------------------------------
// Gather K head-view rows into sorted edge order:
//   Ksort[h][j][0:128] = KMview[h][sorted_e[j]][0:128]
// (view row e of head h starts at flat offset h*EE*CC + e*CC)
// ---------------------------------------------------------------------------
__global__ __launch_bounds__(256)
void gather_k(const ushort_t* __restrict__ KM, ushort_t* __restrict__ Ksort,
              const int* __restrict__ sorted_e)
{
    const size_t hb = (size_t)blockIdx.z * EE * CC;
    const int j  = blockIdx.x * 16 + (threadIdx.x >> 4);
    const int l8 = (threadIdx.x & 15) * 8;
    const int e  = sorted_e[j];
    *(short8*)(Ksort + hb + (size_t)j * CC + l8) =
        *(const short8*)(KM + hb + (size_t)e * CC + l8);
}

// per-head V transpose WITH sorted-row gather:
//   VT[h][c][j] = VMview[h][sorted_e[j]][c]
__global__ void transpose_v(const ushort_t* __restrict__ VM, ushort_t* __restrict__ VT,
                            const int* __restrict__ sorted_e)
{
    __shared__ ushort_t t[32][33];
    const ushort_t* in = VM + (size_t)blockIdx.z * EE * CC;
    ushort_t* out      = VT + (size_t)blockIdx.z * EE * CC;
    const int bx = blockIdx.x * 32;   // col tile over CC
    const int by = blockIdx.y * 32;   // row tile over EE (sorted j)
    const int tx = threadIdx.x, ty = threadIdx.y;
#pragma unroll
    for (int i = 0; i < 32; i += 8) {
        const long rg = sorted_e[by + ty + i];
        t[ty + i][tx] = in[rg * CC + bx + tx];
    }
    __syncthreads();
#pragma unroll
    for (int i = 0; i < 32; i += 8)
        out[(long)(bx + ty + i) * EE + by + tx] = t[tx][ty + i];
}

// ---------------------------------------------------------------------------
// Generic NT GEMM: C[M,N] = epi(A[M,K] * B[N,K]^T), bf16 in, MFMA 16x16x32.
// 128x128 tile, BK=64, 256 threads (4 waves, 2x2).
// Staging via global_load_lds width=16. Split-K via blockIdx.z.
// ---------------------------------------------------------------------------
template <int EPI, bool GATHER>
__global__ __launch_bounds__(256, 2)
void gemm_nt(const ushort_t* __restrict__ A, long lda,
             const ushort_t* __restrict__ B, long ldb,
             const int* __restrict__ gidx,
             const float* __restrict__ bias,
             void* __restrict__ Cp, long ldc,
             int kchunk, float alpha)
{
    __shared__ __align__(16) ushort_t As[BM * BKK];
    __shared__ __align__(16) ushort_t Bs[BN * BKK];

    const int tid  = threadIdx.x;
    const int lane = tid & 63;
    const int wave = tid >> 6;
    const long bm  = (long)blockIdx.x * BM;
    const long bn  = (long)blockIdx.y * BN;
    const int k0   = blockIdx.z * kchunk;
    const int k1   = k0 + kchunk;

    const f32x4 fzero = {0.f, 0.f, 0.f, 0.f};
    f32x4 acc[4][4];
#pragma unroll
    for (int i = 0; i < 4; i++)
#pragma unroll
        for (int j = 0; j < 4; j++) acc[i][j] = fzero;

    const int arow = tid >> 3;          // 0..31
    const int acol = (tid & 7) * 8;

    const ushort_t* ap[4];
    const ushort_t* bp[4];
#pragma unroll
    for (int i = 0; i < 4; i++) {
        long r  = bm + arow + i * 32;
        long gr = GATHER ? (long)gidx[r] : r;
        ap[i] = A + gr * lda + acol;
        bp[i] = B + (bn + arow + i * 32) * ldb + acol;
    }
    const int t8  = tid * 8;
    const int wr  = (wave >> 1) * 64;
    const int wc  = (wave & 1) * 64;
    const int ra  = lane & 15;
    const int kof = (lane >> 4) * 8;

    for (int kt = k0; kt < k1; kt += BKK) {
        __syncthreads();
#pragma unroll
        for (int i = 0; i < 4; i++) GLOAD16(ap[i] + kt, &As[t8 + i * 2048]);
#pragma unroll
        for (int i = 0; i < 4; i++) GLOAD16(bp[i] + kt, &Bs[t8 + i * 2048]);
        __syncthreads();
#pragma unroll
        for (int ks = 0; ks < 2; ks++) {
            short8 af[4], bfr[4];
#pragma unroll
            for (int mi = 0; mi < 4; mi++)
                af[mi] = *(const short8*)&As[(wr + mi * 16 + ra) * BKK + ks * 32 + kof];
#pragma unroll
            for (int ni = 0; ni < 4; ni++)
                bfr[ni] = *(const short8*)&Bs[(wc + ni * 16 + ra) * BKK + ks * 32 + kof];
#pragma unroll
            for (int mi = 0; mi < 4; mi++)
#pragma unroll
                for (int ni = 0; ni < 4; ni++)
                    acc[mi][ni] = __builtin_amdgcn_mfma_f32_16x16x32_bf16(
                        af[mi], bfr[ni], acc[mi][ni], 0, 0, 0);
        }
    }

#pragma unroll
    for (int mi = 0; mi < 4; mi++) {
#pragma unroll
        for (int ni = 0; ni < 4; ni++) {
            const long row0 = bm + wr + mi * 16 + (lane >> 4) * 4;
            const long col  = bn + wc + ni * 16 + ra;
#pragma unroll
            for (int r = 0; r < 4; r++) {
                float v = acc[mi][ni][r];
                const long o = (row0 + r) * ldc + col;
                if (EPI == EPI_STORE_BIAS) {
                    v += bias[col];
                    ((ushort_t*)Cp)[o] = f2b(v);
                } else if (EPI == EPI_EXP) {
                    ((ushort_t*)Cp)[o] = f2b(__expf(v * alpha));
                } else if (EPI == EPI_GELU) {
                    v += bias[col];
                    float g = 0.5f * v * (1.f + erff(v * 0.70710678118654752f));
                    ((ushort_t*)Cp)[o] = f2b(g);
                } else { // EPI_ATOMIC
                    unsafeAtomicAdd(&((float*)Cp)[o], v);
                }
            }
        }
    }
}

// ---------------------------------------------------------------------------
// Segmented softmax normalize on SORTED-column P (segments are contiguous
// runs). One block per row; thread t owns targets [8t,8t+8): sum contiguous
// span, multiply by reciprocal. No LDS, no barriers, no atomics, no idx.
// ---------------------------------------------------------------------------
__global__ __launch_bounds__(256)
void seg_norm_sorted(ushort_t* __restrict__ P, const int* __restrict__ seg_off)
{
    ushort_t* row = P + (long)blockIdx.x * EE;
    const int t8 = threadIdx.x * 8;
    const int sb0 = seg_off[t8];
    float d[8];
    int   ends[8];
    int prev = sb0;
#pragma unroll
    for (int j = 0; j < 8; j++) {
        const int e1 = seg_off[t8 + j + 1];
        float s = 0.f;
        for (int e = prev; e < e1; e++) s += b2f(row[e]);
        d[j] = 1.f / (s + 1e-16f);
        ends[j] = e1;
        prev = e1;
    }
    prev = sb0;
#pragma unroll
    for (int j = 0; j < 8; j++) {
        for (int e = prev; e < ends[j]; e++)
            row[e] = f2b(b2f(row[e]) * d[j]);
        prev = ends[j];
    }
}

// scoreF [NN,HCC] f32 -> bf16
__global__ void cvt_sb(const float* __restrict__ in, ushort_t* __restrict__ out)
{
    long i = (long)blockIdx.x * 256 + threadIdx.x;
    out[i] = f2b(in[i]);
}

// u = u + bias[c] + x (f32), accumulate global sum and sumsq
__global__ __launch_bounds__(256)
void add_bias_x_reduce(float* __restrict__ u, const float* __restrict__ bias,
                       const float* __restrict__ x, float* __restrict__ red)
{
    long i = (long)blockIdx.x * 256 + threadIdx.x;
    float v = u[i] + bias[i & (CC - 1)] + x[i];
    u[i] = v;
    float s = v, s2 = v * v;
#pragma unroll
    for (int o = 32; o > 0; o >>= 1) {
        s  += __shfl_down(s, o, 64);
        s2 += __shfl_down(s2, o, 64);
    }
    __shared__ float ps[4], ps2[4];
    int w = threadIdx.x >> 6;
    if ((threadIdx.x & 63) == 0) { ps[w] = s; ps2[w] = s2; }
    __syncthreads();
    if (threadIdx.x == 0) {
        float a = 0.f, b = 0.f;
#pragma unroll
        for (int j = 0; j < 4; j++) { a += ps[j]; b += ps2[j]; }
        unsafeAtomicAdd(&red[0], a);
        unsafeAtomicAdd(&red[1], b);
    }
}

// middle LN -> bf16 buffer
__global__ void ln_fin_mid(const float* __restrict__ u, const float* __restrict__ red,
                           const float* __restrict__ w, const float* __restrict__ b,
                           ushort_t* __restrict__ out, float invn)
{
    long i = (long)blockIdx.x * 256 + threadIdx.x;
    float mean = red[0] * invn;
    float var  = red[1] * invn - mean * mean;
    float rs   = rsqrtf(var + 1e-5f);
    int c = (int)(i & (CC - 1));
    out[i] = f2b((u[i] - mean) * rs * w[c] + b[c]);
}

// final LN -> d_out in probed dtype
__global__ void ln_fin_out(const float* __restrict__ u, const float* __restrict__ red,
                           const float* __restrict__ w, const float* __restrict__ b,
                           void* __restrict__ out, const int* __restrict__ flags,
                           float invn)
{
    long i = (long)blockIdx.x * 256 + threadIdx.x;
    float mean = red[0] * invn;
    float var  = red[1] * invn - mean * mean;
    float rs   = rsqrtf(var + 1e-5f);
    int c = (int)(i & (CC - 1));
    float v = (u[i] - mean) * rs * w[c] + b[c];
    if (flags[0]) ((float*)out)[i] = v;
    else          ((ushort_t*)out)[i] = f2b(v);
}

// ---------------------------------------------------------------------------
extern "C" void kernel_launch(void* const* d_in, const int* in_sizes, int n_in,
                              void* d_out, int out_size, void* d_ws, size_t ws_size,
                              hipStream_t stream)
{
    const void* x_raw   = d_in[0];
    const void* idx_raw = d_in[1];
    const void* Wq = d_in[2];  const void* bq = d_in[3];
    const void* Wk = d_in[4];  const void* bk = d_in[5];
    const void* Wv = d_in[6];  const void* bv = d_in[7];
    const void* Wz = d_in[8];  const void* bz = d_in[9];
    const void* lnw = d_in[10]; const void* lnb = d_in[11];
    const void* W1 = d_in[12]; const void* b1 = d_in[13];
    const void* W2 = d_in[14]; const void* b2 = d_in[15];
    const void* W3 = d_in[16]; const void* b3 = d_in[17];

    char* ws = (char*)d_ws;
    size_t off = 0;
    auto carve = [&](size_t bytes) -> char* {
        char* p = ws + off;
        off += (bytes + 255) & ~(size_t)255;
        return p;
    };

    // ---- persistent region (~6 MB) ----
    int*      flags  = (int*)     carve(256);
    int*      idx32  = (int*)     carve((size_t)EE * 4);
    int*      sortedE= (int*)     carve((size_t)EE * 4);
    int*      segOff = (int*)     carve((size_t)(NN + 1) * 4);
    ushort_t* x_bf  = (ushort_t*)carve((size_t)NN * CC * 2);
    float*    x_f   = (float*)   carve((size_t)NN * CC * 4);
    float*    vecF  = (float*)   carve(6144 * 4);
    float*    bqF  = vecF;        float* bkF  = vecF + 512;
    float*    bvF  = vecF + 1024; float* bzF  = vecF + 1536;
    float*    lnwF = vecF + 1664; float* lnbF = vecF + 1792;
    float*    b3F  = vecF + 1920; float* b1F  = vecF + 2048;
    float*    b2F  = vecF + 4096;
    ushort_t* wqkvT = (ushort_t*)carve((size_t)3 * HCC * CC * 2);
    ushort_t* wqT = wqkvT;
    ushort_t* wkT = wqkvT + (size_t)HCC * CC;
    ushort_t* wvT = wqkvT + (size_t)2 * HCC * CC;
    ushort_t* wzT   = (ushort_t*)carve((size_t)CC * HCC * 2);
    ushort_t* scoreB= (ushort_t*)carve((size_t)NN * HCC * 2);
    float*    zF    = (float*)   carve((size_t)NN * CC * 4);
    ushort_t* zln   = (ushort_t*)carve((size_t)NN * CC * 2);
    float*    ffnF  = (float*)   carve((size_t)NN * CC * 4);
    float*    red   = (float*)   carve(256);

    // ---- attention scratch (~70 MB), overlaid by FFN scratch (~25 MB) ----
    size_t scratch0 = off;
    ushort_t* QM    = (ushort_t*)carve((size_t)NN * HCC * 2);   // 2 MB
    ushort_t* KM    = (ushort_t*)carve((size_t)EE * HCC * 2);   // 8 MB
    ushort_t* VM    = (ushort_t*)carve((size_t)EE * HCC * 2);   // 8 MB
    ushort_t* Ksort = (ushort_t*)carve((size_t)EE * HCC * 2);   // 8 MB
    ushort_t* VT    = (ushort_t*)carve((size_t)EE * HCC * 2);   // 8 MB
    float*    scoreF= (float*)   carve((size_t)NN * HCC * 4);   // 4 MB
    ushort_t* P     = (ushort_t*)carve((size_t)NN * EE * 2);    // 32 MB
    size_t total_attn = off;
    off = scratch0;
    ushort_t* w1T = (ushort_t*)carve((size_t)DFF * CC * 2);
    ushort_t* w2T = (ushort_t*)carve((size_t)DFF * DFF * 2);
    ushort_t* w3T = (ushort_t*)carve((size_t)CC * DFF * 2);
    ushort_t* h1  = (ushort_t*)carve((size_t)NN * DFF * 2);
    ushort_t* h2  = (ushort_t*)carve((size_t)NN * DFF * 2);
    size_t total_ffn = off;

    size_t required = total_attn > total_ffn ? total_attn : total_ffn;
    if (ws_size < required) return;   // diagnostic: absmax ~5 => ws too small

    // ---- canonicalization + edge sort ----
    probe_k<<<1, 64, 0, stream>>>(x_raw, idx_raw, flags);
    cvt_idx<<<EE / 256, 256, 0, stream>>>(idx_raw, idx32, flags);
    sort_edges<<<1, 256, 0, stream>>>(idx32, sortedE, segOff);
    cvt_x<<<(NN * CC) / 256, 256, 0, stream>>>(x_raw, x_bf, x_f, flags);
    cvt_vecs<<<24, 256, 0, stream>>>(bq, bk, bv, bz, lnw, lnb, b3, b1, b2,
                                     vecF, flags);

    dim3 tb(32, 8);
    transpose_qkv<<<dim3(HCC / 32, CC / 32, 3), tb, 0, stream>>>(Wq, Wk, Wv,
                                                                 wqkvT, flags);
    transpose_cvt<<<dim3(CC / 32, HCC / 32), tb, 0, stream>>>(Wz, wzT, HCC, CC, flags);

    hipMemsetAsync(scoreF, 0, (size_t)NN * HCC * 4, stream);
    hipMemsetAsync(zF,     0, (size_t)NN * CC * 4, stream);
    hipMemsetAsync(ffnF,   0, (size_t)NN * CC * 4, stream);
    hipMemsetAsync(red,    0, 16, stream);

    // ---- projections ----
    gemm_nt<EPI_STORE_BIAS, false><<<dim3(NN / BM, HCC / BN, 1), 256, 0, stream>>>(
        x_bf, CC, wqT, CC, nullptr, bqF, QM, HCC, CC, 0.f);
    gemm_nt<EPI_STORE_BIAS, true><<<dim3(EE / BM, HCC / BN, 1), 256, 0, stream>>>(
        x_bf, CC, wkT, CC, idx32, bkF, KM, HCC, CC, 0.f);
    gemm_nt<EPI_STORE_BIAS, true><<<dim3(EE / BM, HCC / BN, 1), 256, 0, stream>>>(
        x_bf, CC, wvT, CC, idx32, bvF, VM, HCC, CC, 0.f);

    // edge-sort the K head-views; fold sort into V transpose
    gather_k<<<dim3(EE / 16, 1, 4), 256, 0, stream>>>(KM, Ksort, sortedE);
    transpose_v<<<dim3(CC / 32, EE / 32, 4), tb, 0, stream>>>(VM, VT, sortedE);

    const float alpha = 0.088388347648318447f;  // 1/sqrt(128)

    for (int h = 0; h < 4; h++) {
        const size_t hoff = (size_t)h * EE * CC;
        // P = exp(Q_h Ksort_h^T / sqrt(C)) : [2048, 8192], sorted columns
        gemm_nt<EPI_EXP, false><<<dim3(NN / BM, EE / BN, 1), 256, 0, stream>>>(
            QM + (size_t)h * NN * CC, CC, Ksort + hoff, CC,
            nullptr, nullptr, P, EE, CC, alpha);
        seg_norm_sorted<<<NN, 256, 0, stream>>>(P, segOff);
        gemm_nt<EPI_ATOMIC, false><<<dim3(NN / BM, 1, 16), 256, 0, stream>>>(
            P, EE, VT + hoff, EE, nullptr, nullptr,
            scoreF + h * CC, HCC, EE / 16, 0.f);
    }

    cvt_sb<<<(NN * HCC) / 256, 256, 0, stream>>>(scoreF, scoreB);

    // ---- FFN weight transposes (overlay region: P now dead) ----
    transpose_cvt<<<dim3(DFF / 32, CC / 32),  tb, 0, stream>>>(W1, w1T, CC, DFF, flags);
    transpose_cvt<<<dim3(DFF / 32, DFF / 32), tb, 0, stream>>>(W2, w2T, DFF, DFF, flags);
    transpose_cvt<<<dim3(CC / 32, DFF / 32),  tb, 0, stream>>>(W3, w3T, DFF, CC, flags);

    // z = score @ Wz (split-K 8)
    gemm_nt<EPI_ATOMIC, false><<<dim3(NN / BM, 1, 8), 256, 0, stream>>>(
        scoreB, HCC, wzT, HCC, nullptr, nullptr, zF, CC, HCC / 8, 0.f);
    add_bias_x_reduce<<<(NN * CC) / 256, 256, 0, stream>>>(zF, bzF, x_f, red);
    ln_fin_mid<<<(NN * CC) / 256, 256, 0, stream>>>(zF, red, lnwF, lnbF, zln,
                                                    1.f / (float)(NN * CC));

    // ---- FFN ----
    gemm_nt<EPI_GELU, false><<<dim3(NN / BM, DFF / BN, 1), 256, 0, stream>>>(
        zln, CC, w1T, CC, nullptr, b1F, h1, DFF, CC, 0.f);
    gemm_nt<EPI_GELU, false><<<dim3(NN / BM, DFF / BN, 1), 256, 0, stream>>>(
        h1, DFF, w2T, DFF, nullptr, b2F, h2, DFF, DFF, 0.f);
    gemm_nt<EPI_ATOMIC, false><<<dim3(NN / BM, 1, 16), 256, 0, stream>>>(
        h2, DFF, w3T, DFF, nullptr, nullptr, ffnF, CC, DFF / 16, 0.f);
    add_bias_x_reduce<<<(NN * CC) / 256, 256, 0, stream>>>(ffnF, b3F, x_f, red + 2);
    ln_fin_out<<<(NN * CC) / 256, 256, 0, stream>>>(ffnF, red + 2, lnwF, lnbF,
                                                    d_out, flags,
                                                    1.f / (float)(NN * CC));
}

// Round 9
// 500.118 us; speedup vs baseline: 1.7986x; 1.7986x over previous
//
#include <hip/hip_runtime.h>

typedef unsigned short ushort_t;
typedef short short8 __attribute__((ext_vector_type(8)));
typedef float f32x4 __attribute__((ext_vector_type(4)));

// problem constants
#define NN   2048     // nodes
#define EE   8192     // edges
#define CC   128      // channels
#define HCC  512      // H*C
#define DFF  2048

#define BM 128
#define BN 128
#define BKK 64

enum { EPI_STORE_BIAS = 0, EPI_EXP = 1, EPI_GELU = 2, EPI_ATOMIC = 3 };

__device__ __forceinline__ float b2f(ushort_t u) {
    return __uint_as_float(((unsigned int)u) << 16);
}
__device__ __forceinline__ ushort_t f2b(float f) {
    unsigned int u = __float_as_uint(f);
    u += 0x7fffu + ((u >> 16) & 1u);   // round-to-nearest-even
    return (ushort_t)(u >> 16);
}

#define GLOAD16(gp, lp)                                                        \
    __builtin_amdgcn_global_load_lds(                                          \
        (const __attribute__((address_space(1))) unsigned int*)(gp),           \
        (__attribute__((address_space(3))) unsigned int*)(lp), 16, 0, 0)

// ---------------------------------------------------------------------------
// dtype probe: flags[0]=1 if float tensors are f32 (else bf16),
//              flags[1]=1 if index is int64 (else int32)
// ---------------------------------------------------------------------------
__global__ void probe_k(const void* __restrict__ x, const void* __restrict__ idx,
                        int* __restrict__ flags)
{
    if (threadIdx.x == 0 && blockIdx.x == 0) {
        const ushort_t* xu = (const ushort_t*)x;
        float mx = 0.f;
        for (int i = 0; i < 512; i++) {
            float v = fabsf(b2f(xu[i]));
            if (v < 1e30f) mx = fmaxf(mx, v);
            else mx = 1e30f;
        }
        flags[0] = (mx > 1e4f) ? 1 : 0;
        const int* ii = (const int*)idx;
        int allz = 1;
        for (int j = 1; j < 16; j += 2)
            if (ii[j] != 0) allz = 0;
        flags[1] = allz;
    }
}

__global__ void cvt_idx(const void* __restrict__ in, int* __restrict__ out,
                        const int* __restrict__ flags)
{
    int i = blockIdx.x * 256 + threadIdx.x;
    if (i < EE)
        out[i] = flags[1] ? (int)((const long long*)in)[i] : ((const int*)in)[i];
}

// ---------------------------------------------------------------------------
// Counting sort of edges by target. Also emits sseg[pos] = target of sorted
// position pos (non-decreasing), used for the coalesced normalize gather.
// ---------------------------------------------------------------------------
__global__ __launch_bounds__(256)
void sort_edges(const int* __restrict__ idx, int* __restrict__ sorted_e,
                int* __restrict__ seg_off, int* __restrict__ sseg)
{
    __shared__ int hist[NN];
    __shared__ int cursor[NN];
    __shared__ float wsum[4];
    const int tid = threadIdx.x;
    for (int i = tid; i < NN; i += 256) hist[i] = 0;
    __syncthreads();
    for (int e = tid; e < EE; e += 256) atomicAdd(&hist[idx[e]], 1);
    __syncthreads();
    int s = 0;
#pragma unroll
    for (int j = 0; j < 8; j++) s += hist[tid * 8 + j];
    int lane = tid & 63, w = tid >> 6;
    int sc = s;
#pragma unroll
    for (int o = 1; o < 64; o <<= 1) {
        int t = __shfl_up(sc, o, 64);
        if (lane >= o) sc += t;
    }
    if (lane == 63) wsum[w] = (float)sc;
    __syncthreads();
    int wbase = 0;
    for (int j = 0; j < 4; j++) if (j < w) wbase += (int)wsum[j];
    int excl = wbase + sc - s;
    int run = excl;
#pragma unroll
    for (int j = 0; j < 8; j++) {
        int b = tid * 8 + j;
        cursor[b] = run;
        seg_off[b] = run;
        run += hist[b];
    }
    if (tid == 0) seg_off[NN] = EE;
    __syncthreads();
    for (int e = tid; e < EE; e += 256) {
        int t = idx[e];
        int pos = atomicAdd(&cursor[t], 1);
        sorted_e[pos] = e;
        sseg[pos] = t;
    }
}

// x -> bf16 copy (for MFMA) and f32 copy (for residual/LN)
__global__ void cvt_x(const void* __restrict__ in, ushort_t* __restrict__ xb,
                      float* __restrict__ xf, const int* __restrict__ flags)
{
    long i = (long)blockIdx.x * 256 + threadIdx.x;   // NN*CC
    float v = flags[0] ? ((const float*)in)[i] : b2f(((const ushort_t*)in)[i]);
    xf[i] = v;
    xb[i] = f2b(v);
}

// all 9 small vectors -> one canonical f32 buffer
__global__ void cvt_vecs(const void* bq, const void* bk, const void* bv,
                         const void* bz, const void* lnw, const void* lnb,
                         const void* b3, const void* b1, const void* b2,
                         float* __restrict__ out, const int* __restrict__ flags)
{
    int i = blockIdx.x * 256 + threadIdx.x;
    if (i >= 6144) return;
    const void* src; int o;
    if      (i < 512)  { src = bq;  o = i; }
    else if (i < 1024) { src = bk;  o = i - 512; }
    else if (i < 1536) { src = bv;  o = i - 1024; }
    else if (i < 1664) { src = bz;  o = i - 1536; }
    else if (i < 1792) { src = lnw; o = i - 1664; }
    else if (i < 1920) { src = lnb; o = i - 1792; }
    else if (i < 2048) { src = b3;  o = i - 1920; }
    else if (i < 4096) { src = b1;  o = i - 2048; }
    else               { src = b2;  o = i - 4096; }
    out[i] = flags[0] ? ((const float*)src)[o] : b2f(((const ushort_t*)src)[o]);
}

// weight transpose + convert to bf16: in [R,C] -> out [C,R] bf16
__global__ void transpose_cvt(const void* __restrict__ in, ushort_t* __restrict__ out,
                              int R, int C, const int* __restrict__ flags)
{
    __shared__ ushort_t t[32][33];
    const int f  = flags[0];
    const int bx = blockIdx.x * 32;
    const int by = blockIdx.y * 32;
    const int tx = threadIdx.x, ty = threadIdx.y;
#pragma unroll
    for (int i = 0; i < 32; i += 8) {
        long src = (long)(by + ty + i) * C + bx + tx;
        t[ty + i][tx] = f ? f2b(((const float*)in)[src]) : ((const ushort_t*)in)[src];
    }
    __syncthreads();
#pragma unroll
    for (int i = 0; i < 32; i += 8)
        out[(long)(bx + ty + i) * R + by + tx] = t[tx][ty + i];
}

// batched Wq/Wk/Wv transpose (all [128,512] -> [512,128])
__global__ void transpose_qkv(const void* q, const void* k, const void* v,
                              ushort_t* __restrict__ out, const int* __restrict__ flags)
{
    __shared__ ushort_t t[32][33];
    const void* in = blockIdx.z == 0 ? q : (blockIdx.z == 1 ? k : v);
    const int f  = flags[0];
    const int bx = blockIdx.x * 32;
    const int by = blockIdx.y * 32;
    const int tx = threadIdx.x, ty = threadIdx.y;
#pragma unroll
    for (int i = 0; i < 32; i += 8) {
        long src = (long)(by + ty + i) * HCC + bx + tx;
        t[ty + i][tx] = f ? f2b(((const float*)in)[src]) : ((const ushort_t*)in)[src];
    }
    __syncthreads();
#pragma unroll
    for (int i = 0; i < 32; i += 8)
        out[(size_t)blockIdx.z * HCC * CC + (long)(bx + ty + i) * CC + by + tx]
            = t[tx][ty + i];
}

// ---------------------------------------------------------------------------
// Gather K head-view rows into sorted edge order.
// ---------------------------------------------------------------------------
__global__ __launch_bounds__(256)
void gather_k(const ushort_t* __restrict__ KM, ushort_t* __restrict__ Ksort,
              const int* __restrict__ sorted_e)
{
    const size_t hb = (size_t)blockIdx.z * EE * CC;
    const int j  = blockIdx.x * 16 + (threadIdx.x >> 4);
    const int l8 = (threadIdx.x & 15) * 8;
    const int e  = sorted_e[j];
    *(short8*)(Ksort + hb + (size_t)j * CC + l8) =
        *(const short8*)(KM + hb + (size_t)e * CC + l8);
}

// per-head V transpose WITH sorted-row gather: VT[h][c][j] = VM[h][sorted_e[j]][c]
__global__ void transpose_v(const ushort_t* __restrict__ VM, ushort_t* __restrict__ VT,
                            const int* __restrict__ sorted_e)
{
    __shared__ ushort_t t[32][33];
    const ushort_t* in = VM + (size_t)blockIdx.z * EE * CC;
    ushort_t* out      = VT + (size_t)blockIdx.z * EE * CC;
    const int bx = blockIdx.x * 32;   // col tile over CC
    const int by = blockIdx.y * 32;   // row tile over EE (sorted j)
    const int tx = threadIdx.x, ty = threadIdx.y;
#pragma unroll
    for (int i = 0; i < 32; i += 8) {
        const long rg = sorted_e[by + ty + i];
        t[ty + i][tx] = in[rg * CC + bx + tx];
    }
    __syncthreads();
#pragma unroll
    for (int i = 0; i < 32; i += 8)
        out[(long)(bx + ty + i) * EE + by + tx] = t[tx][ty + i];
}

// ---------------------------------------------------------------------------
// Generic NT GEMM: C[M,N] = epi(A[M,K] * B[N,K]^T), bf16 in, MFMA 16x16x32.
// 128x128 tile, BK=64, 256 threads (4 waves, 2x2).
// Staging via global_load_lds width=16. Split-K via blockIdx.z.
// ---------------------------------------------------------------------------
template <int EPI, bool GATHER>
__global__ __launch_bounds__(256, 2)
void gemm_nt(const ushort_t* __restrict__ A, long lda,
             const ushort_t* __restrict__ B, long ldb,
             const int* __restrict__ gidx,
             const float* __restrict__ bias,
             void* __restrict__ Cp, long ldc,
             int kchunk, float alpha)
{
    __shared__ __align__(16) ushort_t As[BM * BKK];
    __shared__ __align__(16) ushort_t Bs[BN * BKK];

    const int tid  = threadIdx.x;
    const int lane = tid & 63;
    const int wave = tid >> 6;
    const long bm  = (long)blockIdx.x * BM;
    const long bn  = (long)blockIdx.y * BN;
    const int k0   = blockIdx.z * kchunk;
    const int k1   = k0 + kchunk;

    const f32x4 fzero = {0.f, 0.f, 0.f, 0.f};
    f32x4 acc[4][4];
#pragma unroll
    for (int i = 0; i < 4; i++)
#pragma unroll
        for (int j = 0; j < 4; j++) acc[i][j] = fzero;

    const int arow = tid >> 3;          // 0..31
    const int acol = (tid & 7) * 8;

    const ushort_t* ap[4];
    const ushort_t* bp[4];
#pragma unroll
    for (int i = 0; i < 4; i++) {
        long r  = bm + arow + i * 32;
        long gr = GATHER ? (long)gidx[r] : r;
        ap[i] = A + gr * lda + acol;
        bp[i] = B + (bn + arow + i * 32) * ldb + acol;
    }
    const int t8  = tid * 8;
    const int wr  = (wave >> 1) * 64;
    const int wc  = (wave & 1) * 64;
    const int ra  = lane & 15;
    const int kof = (lane >> 4) * 8;

    for (int kt = k0; kt < k1; kt += BKK) {
        __syncthreads();
#pragma unroll
        for (int i = 0; i < 4; i++) GLOAD16(ap[i] + kt, &As[t8 + i * 2048]);
#pragma unroll
        for (int i = 0; i < 4; i++) GLOAD16(bp[i] + kt, &Bs[t8 + i * 2048]);
        __syncthreads();
#pragma unroll
        for (int ks = 0; ks < 2; ks++) {
            short8 af[4], bfr[4];
#pragma unroll
            for (int mi = 0; mi < 4; mi++)
                af[mi] = *(const short8*)&As[(wr + mi * 16 + ra) * BKK + ks * 32 + kof];
#pragma unroll
            for (int ni = 0; ni < 4; ni++)
                bfr[ni] = *(const short8*)&Bs[(wc + ni * 16 + ra) * BKK + ks * 32 + kof];
#pragma unroll
            for (int mi = 0; mi < 4; mi++)
#pragma unroll
                for (int ni = 0; ni < 4; ni++)
                    acc[mi][ni] = __builtin_amdgcn_mfma_f32_16x16x32_bf16(
                        af[mi], bfr[ni], acc[mi][ni], 0, 0, 0);
        }
    }

#pragma unroll
    for (int mi = 0; mi < 4; mi++) {
#pragma unroll
        for (int ni = 0; ni < 4; ni++) {
            const long row0 = bm + wr + mi * 16 + (lane >> 4) * 4;
            const long col  = bn + wc + ni * 16 + ra;
#pragma unroll
            for (int r = 0; r < 4; r++) {
                float v = acc[mi][ni][r];
                const long o = (row0 + r) * ldc + col;
                if (EPI == EPI_STORE_BIAS) {
                    v += bias[col];
                    ((ushort_t*)Cp)[o] = f2b(v);
                } else if (EPI == EPI_EXP) {
                    ((ushort_t*)Cp)[o] = f2b(__expf(v * alpha));
                } else if (EPI == EPI_GELU) {
                    v += bias[col];
                    float g = 0.5f * v * (1.f + erff(v * 0.70710678118654752f));
                    ((ushort_t*)Cp)[o] = f2b(g);
                } else { // EPI_ATOMIC
                    unsafeAtomicAdd(&((float*)Cp)[o], v);
                }
            }
        }
    }
}

// ---------------------------------------------------------------------------
// Segmented softmax normalize on SORTED-column P. Round-8 version walked
// spans per-lane -> uncoalesced 2B traffic -> 251MB HBM writes (16x ampl).
// v2: LDS-staged. (1) coalesced short8 row load -> f32 LDS; (2) thread t
// sums segments [8t,8t+8) from LDS (divergent LDS reads are cheap), plain
// store D[t]; (3) coalesced normalize via sseg gather, coalesced store.
// ---------------------------------------------------------------------------
__global__ __launch_bounds__(256)
void seg_norm_sorted(ushort_t* __restrict__ P, const int* __restrict__ seg_off,
                     const int* __restrict__ sseg)
{
    __shared__ float rowf[EE];   // 32 KB
    __shared__ float D[NN];      //  8 KB
    ushort_t* row = P + (long)blockIdx.x * EE;
    const int tid = threadIdx.x;

#pragma unroll
    for (int c = 0; c < 4; c++) {
        const int e = c * 2048 + tid * 8;
        short8 v = *(const short8*)(row + e);
#pragma unroll
        for (int j = 0; j < 8; j++)
            rowf[e + j] = b2f((ushort_t)v[j]);
    }
    __syncthreads();

    const int t8 = tid * 8;
    int prev = seg_off[t8];
#pragma unroll
    for (int j = 0; j < 8; j++) {
        const int e1 = seg_off[t8 + j + 1];
        float s = 0.f;
        for (int e = prev; e < e1; e++) s += rowf[e];
        D[t8 + j] = 1.f / (s + 1e-16f);
        prev = e1;
    }
    __syncthreads();

#pragma unroll
    for (int c = 0; c < 4; c++) {
        const int e = c * 2048 + tid * 8;
        short8 o;
#pragma unroll
        for (int j = 0; j < 8; j++)
            o[j] = (short)f2b(rowf[e + j] * D[sseg[e + j]]);
        *(short8*)(row + e) = o;
    }
}

// scoreF [NN,HCC] f32 -> bf16
__global__ void cvt_sb(const float* __restrict__ in, ushort_t* __restrict__ out)
{
    long i = (long)blockIdx.x * 256 + threadIdx.x;
    out[i] = f2b(in[i]);
}

// u = u + bias[c] + x (f32), accumulate global sum and sumsq
__global__ __launch_bounds__(256)
void add_bias_x_reduce(float* __restrict__ u, const float* __restrict__ bias,
                       const float* __restrict__ x, float* __restrict__ red)
{
    long i = (long)blockIdx.x * 256 + threadIdx.x;
    float v = u[i] + bias[i & (CC - 1)] + x[i];
    u[i] = v;
    float s = v, s2 = v * v;
#pragma unroll
    for (int o = 32; o > 0; o >>= 1) {
        s  += __shfl_down(s, o, 64);
        s2 += __shfl_down(s2, o, 64);
    }
    __shared__ float ps[4], ps2[4];
    int w = threadIdx.x >> 6;
    if ((threadIdx.x & 63) == 0) { ps[w] = s; ps2[w] = s2; }
    __syncthreads();
    if (threadIdx.x == 0) {
        float a = 0.f, b = 0.f;
#pragma unroll
        for (int j = 0; j < 4; j++) { a += ps[j]; b += ps2[j]; }
        unsafeAtomicAdd(&red[0], a);
        unsafeAtomicAdd(&red[1], b);
    }
}

// middle LN -> bf16 buffer
__global__ void ln_fin_mid(const float* __restrict__ u, const float* __restrict__ red,
                           const float* __restrict__ w, const float* __restrict__ b,
                           ushort_t* __restrict__ out, float invn)
{
    long i = (long)blockIdx.x * 256 + threadIdx.x;
    float mean = red[0] * invn;
    float var  = red[1] * invn - mean * mean;
    float rs   = rsqrtf(var + 1e-5f);
    int c = (int)(i & (CC - 1));
    out[i] = f2b((u[i] - mean) * rs * w[c] + b[c]);
}

// final LN -> d_out in probed dtype
__global__ void ln_fin_out(const float* __restrict__ u, const float* __restrict__ red,
                           const float* __restrict__ w, const float* __restrict__ b,
                           void* __restrict__ out, const int* __restrict__ flags,
                           float invn)
{
    long i = (long)blockIdx.x * 256 + threadIdx.x;
    float mean = red[0] * invn;
    float var  = red[1] * invn - mean * mean;
    float rs   = rsqrtf(var + 1e-5f);
    int c = (int)(i & (CC - 1));
    float v = (u[i] - mean) * rs * w[c] + b[c];
    if (flags[0]) ((float*)out)[i] = v;
    else          ((ushort_t*)out)[i] = f2b(v);
}

// ---------------------------------------------------------------------------
extern "C" void kernel_launch(void* const* d_in, const int* in_sizes, int n_in,
                              void* d_out, int out_size, void* d_ws, size_t ws_size,
                              hipStream_t stream)
{
    const void* x_raw   = d_in[0];
    const void* idx_raw = d_in[1];
    const void* Wq = d_in[2];  const void* bq = d_in[3];
    const void* Wk = d_in[4];  const void* bk = d_in[5];
    const void* Wv = d_in[6];  const void* bv = d_in[7];
    const void* Wz = d_in[8];  const void* bz = d_in[9];
    const void* lnw = d_in[10]; const void* lnb = d_in[11];
    const void* W1 = d_in[12]; const void* b1 = d_in[13];
    const void* W2 = d_in[14]; const void* b2 = d_in[15];
    const void* W3 = d_in[16]; const void* b3 = d_in[17];

    char* ws = (char*)d_ws;
    size_t off = 0;
    auto carve = [&](size_t bytes) -> char* {
        char* p = ws + off;
        off += (bytes + 255) & ~(size_t)255;
        return p;
    };

    // ---- persistent region (~6 MB) ----
    int*      flags  = (int*)     carve(256);
    int*      idx32  = (int*)     carve((size_t)EE * 4);
    int*      sortedE= (int*)     carve((size_t)EE * 4);
    int*      segOff = (int*)     carve((size_t)(NN + 1) * 4);
    int*      ssegB  = (int*)     carve((size_t)EE * 4);
    ushort_t* x_bf  = (ushort_t*)carve((size_t)NN * CC * 2);
    float*    x_f   = (float*)   carve((size_t)NN * CC * 4);
    float*    vecF  = (float*)   carve(6144 * 4);
    float*    bqF  = vecF;        float* bkF  = vecF + 512;
    float*    bvF  = vecF + 1024; float* bzF  = vecF + 1536;
    float*    lnwF = vecF + 1664; float* lnbF = vecF + 1792;
    float*    b3F  = vecF + 1920; float* b1F  = vecF + 2048;
    float*    b2F  = vecF + 4096;
    ushort_t* wqkvT = (ushort_t*)carve((size_t)3 * HCC * CC * 2);
    ushort_t* wqT = wqkvT;
    ushort_t* wkT = wqkvT + (size_t)HCC * CC;
    ushort_t* wvT = wqkvT + (size_t)2 * HCC * CC;
    ushort_t* wzT   = (ushort_t*)carve((size_t)CC * HCC * 2);
    ushort_t* scoreB= (ushort_t*)carve((size_t)NN * HCC * 2);
    float*    zF    = (float*)   carve((size_t)NN * CC * 4);
    ushort_t* zln   = (ushort_t*)carve((size_t)NN * CC * 2);
    float*    ffnF  = (float*)   carve((size_t)NN * CC * 4);
    float*    red   = (float*)   carve(256);

    // ---- attention scratch (~70 MB), overlaid by FFN scratch (~25 MB) ----
    size_t scratch0 = off;
    ushort_t* QM    = (ushort_t*)carve((size_t)NN * HCC * 2);   // 2 MB
    ushort_t* KM    = (ushort_t*)carve((size_t)EE * HCC * 2);   // 8 MB
    ushort_t* VM    = (ushort_t*)carve((size_t)EE * HCC * 2);   // 8 MB
    ushort_t* Ksort = (ushort_t*)carve((size_t)EE * HCC * 2);   // 8 MB
    ushort_t* VT    = (ushort_t*)carve((size_t)EE * HCC * 2);   // 8 MB
    float*    scoreF= (float*)   carve((size_t)NN * HCC * 4);   // 4 MB
    ushort_t* P     = (ushort_t*)carve((size_t)NN * EE * 2);    // 32 MB
    size_t total_attn = off;
    off = scratch0;
    ushort_t* w1T = (ushort_t*)carve((size_t)DFF * CC * 2);
    ushort_t* w2T = (ushort_t*)carve((size_t)DFF * DFF * 2);
    ushort_t* w3T = (ushort_t*)carve((size_t)CC * DFF * 2);
    ushort_t* h1  = (ushort_t*)carve((size_t)NN * DFF * 2);
    ushort_t* h2  = (ushort_t*)carve((size_t)NN * DFF * 2);
    size_t total_ffn = off;

    size_t required = total_attn > total_ffn ? total_attn : total_ffn;
    if (ws_size < required) return;   // diagnostic: absmax ~5 => ws too small

    // ---- canonicalization + edge sort ----
    probe_k<<<1, 64, 0, stream>>>(x_raw, idx_raw, flags);
    cvt_idx<<<EE / 256, 256, 0, stream>>>(idx_raw, idx32, flags);
    sort_edges<<<1, 256, 0, stream>>>(idx32, sortedE, segOff, ssegB);
    cvt_x<<<(NN * CC) / 256, 256, 0, stream>>>(x_raw, x_bf, x_f, flags);
    cvt_vecs<<<24, 256, 0, stream>>>(bq, bk, bv, bz, lnw, lnb, b3, b1, b2,
                                     vecF, flags);

    dim3 tb(32, 8);
    transpose_qkv<<<dim3(HCC / 32, CC / 32, 3), tb, 0, stream>>>(Wq, Wk, Wv,
                                                                 wqkvT, flags);
    transpose_cvt<<<dim3(CC / 32, HCC / 32), tb, 0, stream>>>(Wz, wzT, HCC, CC, flags);

    hipMemsetAsync(scoreF, 0, (size_t)NN * HCC * 4, stream);
    hipMemsetAsync(zF,     0, (size_t)NN * CC * 4, stream);
    hipMemsetAsync(ffnF,   0, (size_t)NN * CC * 4, stream);
    hipMemsetAsync(red,    0, 16, stream);

    // ---- projections ----
    gemm_nt<EPI_STORE_BIAS, false><<<dim3(NN / BM, HCC / BN, 1), 256, 0, stream>>>(
        x_bf, CC, wqT, CC, nullptr, bqF, QM, HCC, CC, 0.f);
    gemm_nt<EPI_STORE_BIAS, true><<<dim3(EE / BM, HCC / BN, 1), 256, 0, stream>>>(
        x_bf, CC, wkT, CC, idx32, bkF, KM, HCC, CC, 0.f);
    gemm_nt<EPI_STORE_BIAS, true><<<dim3(EE / BM, HCC / BN, 1), 256, 0, stream>>>(
        x_bf, CC, wvT, CC, idx32, bvF, VM, HCC, CC, 0.f);

    // edge-sort the K head-views; fold sort into V transpose
    gather_k<<<dim3(EE / 16, 1, 4), 256, 0, stream>>>(KM, Ksort, sortedE);
    transpose_v<<<dim3(CC / 32, EE / 32, 4), tb, 0, stream>>>(VM, VT, sortedE);

    const float alpha = 0.088388347648318447f;  // 1/sqrt(128)

    for (int h = 0; h < 4; h++) {
        const size_t hoff = (size_t)h * EE * CC;
        // P = exp(Q_h Ksort_h^T / sqrt(C)) : [2048, 8192], sorted columns
        gemm_nt<EPI_EXP, false><<<dim3(NN / BM, EE / BN, 1), 256, 0, stream>>>(
            QM + (size_t)h * NN * CC, CC, Ksort + hoff, CC,
            nullptr, nullptr, P, EE, CC, alpha);
        seg_norm_sorted<<<NN, 256, 0, stream>>>(P, segOff, ssegB);
        gemm_nt<EPI_ATOMIC, false><<<dim3(NN / BM, 1, 16), 256, 0, stream>>>(
            P, EE, VT + hoff, EE, nullptr, nullptr,
            scoreF + h * CC, HCC, EE / 16, 0.f);
    }

    cvt_sb<<<(NN * HCC) / 256, 256, 0, stream>>>(scoreF, scoreB);

    // ---- FFN weight transposes (overlay region: P now dead) ----
    transpose_cvt<<<dim3(DFF / 32, CC / 32),  tb, 0, stream>>>(W1, w1T, CC, DFF, flags);
    transpose_cvt<<<dim3(DFF / 32, DFF / 32), tb, 0, stream>>>(W2, w2T, DFF, DFF, flags);
    transpose_cvt<<<dim3(CC / 32, DFF / 32),  tb, 0, stream>>>(W3, w3T, DFF, CC, flags);

    // z = score @ Wz (split-K 8)
    gemm_nt<EPI_ATOMIC, false><<<dim3(NN / BM, 1, 8), 256, 0, stream>>>(
        scoreB, HCC, wzT, HCC, nullptr, nullptr, zF, CC, HCC / 8, 0.f);
    add_bias_x_reduce<<<(NN * CC) / 256, 256, 0, stream>>>(zF, bzF, x_f, red);
    ln_fin_mid<<<(NN * CC) / 256, 256, 0, stream>>>(zF, red, lnwF, lnbF, zln,
                                                    1.f / (float)(NN * CC));

    // ---- FFN ----
    gemm_nt<EPI_GELU, false><<<dim3(NN / BM, DFF / BN, 1), 256, 0, stream>>>(
        zln, CC, w1T, CC, nullptr, b1F, h1, DFF, CC, 0.f);
    gemm_nt<EPI_GELU, false><<<dim3(NN / BM, DFF / BN, 1), 256, 0, stream>>>(
        h1, DFF, w2T, DFF, nullptr, b2F, h2, DFF, DFF, 0.f);
    gemm_nt<EPI_ATOMIC, false><<<dim3(NN / BM, 1, 16), 256, 0, stream>>>(
        h2, DFF, w3T, DFF, nullptr, nullptr, ffnF, CC, DFF / 16, 0.f);
    add_bias_x_reduce<<<(NN * CC) / 256, 256, 0, stream>>>(ffnF, b3F, x_f, red + 2);
    ln_fin_out<<<(NN * CC) / 256, 256, 0, stream>>>(ffnF, red + 2, lnwF, lnbF,
                                                    d_out, flags,
                                                    1.f / (float)(NN * CC));
}